// Round 5
// baseline (250.387 us; speedup 1.0000x reference)
//
#include <hip/hip_runtime.h>
#include <hip/hip_bf16.h>
#include <math.h>

#define XN 262144
#define NPAIR (XN - 1)
#define BN 64
#define HD 256
#define KK 8
#define THRC 1e-6f

__device__ __forceinline__ float gelu_f(float x) {
    return 0.5f * x * (1.0f + erff(x * 0.70710678118654752440f));
}

__device__ __forceinline__ unsigned short f2bf(float f) {
    unsigned int x = __float_as_uint(f);
    unsigned int r = (x + 0x7fffu + ((x >> 16) & 1u)) >> 16;  // RNE
    return (unsigned short)r;
}

// ---------------- Kernel 0: weights fp32 -> bf16 into workspace -------------
// bw layout (ushort): [0, 393216) rb_w1 | [393216, 786432) rb_w2 |
//                     [786432, 819200) out_w1.
__global__ __launch_bounds__(256) void convert_kernel(
    const float* __restrict__ rb_w1, const float* __restrict__ rb_w2,
    const float* __restrict__ out_w1, unsigned short* __restrict__ bw) {
    int t = blockIdx.x * 256 + threadIdx.x;
    const float* s;
    if (t < 49152) s = rb_w1 + (size_t)t * 8;
    else if (t < 98304) s = rb_w2 + (size_t)(t - 49152) * 8;
    else s = out_w1 + (size_t)(t - 98304) * 8;
    float4 a = *(const float4*)s;
    float4 b = *(const float4*)(s + 4);
    union { unsigned short u[8]; uint4 v; } r;
    r.u[0] = f2bf(a.x); r.u[1] = f2bf(a.y); r.u[2] = f2bf(a.z); r.u[3] = f2bf(a.w);
    r.u[4] = f2bf(b.x); r.u[5] = f2bf(b.y); r.u[6] = f2bf(b.z); r.u[7] = f2bf(b.w);
    *(uint4*)(bw + (size_t)t * 8) = r.v;
}

// FMA 8 cols x 2 tokens from one uint4 of bf16
#define BF8_FMA(w, z)                                                        \
    do {                                                                     \
        float f0, f1;                                                        \
        f0 = __uint_as_float((w).x << 16);                                   \
        f1 = __uint_as_float((w).x & 0xffff0000u);                           \
        a0[0] = fmaf(f0, (z).x, a0[0]); a1[0] = fmaf(f0, (z).y, a1[0]);      \
        a0[1] = fmaf(f1, (z).x, a0[1]); a1[1] = fmaf(f1, (z).y, a1[1]);      \
        f0 = __uint_as_float((w).y << 16);                                   \
        f1 = __uint_as_float((w).y & 0xffff0000u);                           \
        a0[2] = fmaf(f0, (z).x, a0[2]); a1[2] = fmaf(f0, (z).y, a1[2]);      \
        a0[3] = fmaf(f1, (z).x, a0[3]); a1[3] = fmaf(f1, (z).y, a1[3]);      \
        f0 = __uint_as_float((w).z << 16);                                   \
        f1 = __uint_as_float((w).z & 0xffff0000u);                           \
        a0[4] = fmaf(f0, (z).x, a0[4]); a1[4] = fmaf(f0, (z).y, a1[4]);      \
        a0[5] = fmaf(f1, (z).x, a0[5]); a1[5] = fmaf(f1, (z).y, a1[5]);      \
        f0 = __uint_as_float((w).w << 16);                                   \
        f1 = __uint_as_float((w).w & 0xffff0000u);                           \
        a0[6] = fmaf(f0, (z).x, a0[6]); a1[6] = fmaf(f0, (z).y, a1[6]);      \
        a0[7] = fmaf(f1, (z).x, a0[7]); a1[7] = fmaf(f1, (z).y, a1[7]);      \
    } while (0)

// ---------------- Kernel 1: fused count + select + MLP -----------------------
// Grid 768 x 512 threads:
//   blocks [0,512):  count. b = blk>>3, slice s = blk&7 (32768 left-ends).
//                    Partial count -> float atomicAdd(out[3072+b]).
//   blocks [512,768): mlp. mb = blk-512; b = mb>>2; sub = mb&3 -> 2 tokens.
//                    Wave 0 runs the first-8 select scan itself (no dep).
__global__ __launch_bounds__(512) void fused_kernel(
    const float* __restrict__ x, const unsigned short* __restrict__ bw,
    const float* __restrict__ w_in, const float* __restrict__ b_in,
    const float* __restrict__ ln_in_g, const float* __restrict__ ln_in_b,
    const float* __restrict__ rb_ln_g, const float* __restrict__ rb_ln_b,
    const float* __restrict__ rb_b1, const float* __restrict__ rb_b2,
    const float* __restrict__ out_ln_g, const float* __restrict__ out_ln_b,
    const float* __restrict__ out_b1,
    const float* __restrict__ out_w2, const float* __restrict__ out_b2,
    float* __restrict__ out) {
    __shared__ float2 hsv[HD];
    __shared__ float2 ztv[HD];
    __shared__ float2 z2tv[2 * HD];
    __shared__ float2 z3tv[HD / 2];
    __shared__ float part[8192];   // 32 KB split-K partials
    __shared__ float red[8][2][2];
    __shared__ float stat[2][2];
    __shared__ float fin[2][4];
    __shared__ float2 suv[2];      // uL/uR for this block's 2 tokens
    __shared__ int sred[8];

    const int blk = blockIdx.x;
    const int tid = threadIdx.x;
    const int lane = tid & 63, wave = tid >> 6;

    if (blk < 512) {
        // ================= count path =================
        const int b = blk >> 3;
        const int s = blk & 7;
        const float* row = x + (size_t)b * 2 * XN;
        int cnt = 0;
        const int base0 = s * 32768;
#pragma unroll
        for (int it = 0; it < 16; ++it) {
            int e0 = base0 + ((it << 9) + tid) * 4;
            float4 f = *(const float4*)(row + e0);
            cnt += (fabsf(f.x - f.y) > THRC);
            cnt += (fabsf(f.y - f.z) > THRC);
            cnt += (fabsf(f.z - f.w) > THRC);
            if (e0 + 4 < XN) {
                float e = row[e0 + 4];
                cnt += (fabsf(f.w - e) > THRC);
            }
        }
#pragma unroll
        for (int off = 32; off > 0; off >>= 1) cnt += __shfl_down(cnt, off, 64);
        if (lane == 0) sred[wave] = cnt;
        __syncthreads();
        if (tid == 0) {
            int t = 0;
#pragma unroll
            for (int w = 0; w < 8; ++w) t += sred[w];
            atomicAdd(&out[3072 + b], (float)t);
        }
        return;
    }

    // ================= mlp path =================
    const int mb = blk - 512;
    const int b = mb >> 2;
    const int sub = mb & 3;
    const float* row = x + (size_t)b * 2 * XN;

    // ---- select scan (wave 0; all lanes end up with idxs/vflag uniform) ----
    if (wave == 0) {
        const float* c = row + XN;
        int idxs[KK];
        float vflag[KK];
        int found = 0;
        for (int base = 0; base < NPAIR && found < KK; base += 64) {
            int i = base + lane;
            bool v = (i < NPAIR) && (fabsf(row[i] - row[i + 1]) > THRC);
            unsigned long long m = __ballot(v);
            while (m && found < KK) {
                int l = __ffsll(m) - 1;
                idxs[found] = base + l;
                vflag[found] = 1.0f;
                ++found;
                m &= (m - 1);
            }
        }
        if (found < KK) {
            for (int base = 0; base < NPAIR && found < KK; base += 64) {
                int i = base + lane;
                bool v = (i < NPAIR) && !(fabsf(row[i] - row[i + 1]) > THRC);
                unsigned long long m = __ballot(v);
                while (m && found < KK) {
                    int l = __ffsll(m) - 1;
                    idxs[found] = base + l;
                    vflag[found] = 0.0f;
                    ++found;
                    m &= (m - 1);
                }
            }
        }
        // stash this block's 2 tokens
        if (lane < 2) {
            int i = idxs[sub * 2 + lane];
            float2 uv;
            uv.x = row[i];
            uv.y = row[i + 1];
            suv[lane] = uv;
        }
        // channels 2..5 written once per row (sub==0)
        if (sub == 0 && lane < KK) {
            int i = idxs[lane];
            float uL = row[i];
            float uR = row[i + 1];
            float fc = (c[i] + c[i + 1]) * 0.5f;
            float* o = out + b * 48;
            o[16 + lane] = uL;
            o[24 + lane] = uR;
            o[32 + lane] = fc;
            o[40 + lane] = vflag[lane];
        }
    }
    __syncthreads();

    // ---- input layer ----
    if (tid < HD) {
        const int c = tid;
        float fw[6];
#pragma unroll
        for (int f = 0; f < 6; ++f) fw[f] = w_in[f * HD + c];
        float bin = b_in[c];
        float2 hv;
        float* hvp = (float*)&hv;
#pragma unroll
        for (int j = 0; j < 2; ++j) {
            float uL = suv[j].x;
            float uR = suv[j].y;
            float dd = uL - uR;
            float sg = (dd > 0.0f) ? 1.0f : ((dd < 0.0f) ? -1.0f : 0.0f);
            hvp[j] = bin + uL * fw[0] + uR * fw[1] + dd * fw[2] +
                     fabsf(dd) * fw[3] + (uL + uR) * 0.5f * fw[4] + sg * fw[5];
        }
        hsv[c] = hv;
    }
    __syncthreads();

#define LN_STATS()                                                            \
    do {                                                                      \
        if (tid < HD) {                                                       \
            float2 h2 = hsv[tid];                                             \
            float s[2] = {h2.x, h2.y};                                        \
            float q[2] = {h2.x * h2.x, h2.y * h2.y};                          \
            for (int off = 32; off > 0; off >>= 1) {                          \
                _Pragma("unroll") for (int j = 0; j < 2; ++j) {               \
                    s[j] += __shfl_down(s[j], off, 64);                       \
                    q[j] += __shfl_down(q[j], off, 64);                       \
                }                                                             \
            }                                                                 \
            if (lane == 0) {                                                  \
                _Pragma("unroll") for (int j = 0; j < 2; ++j) {               \
                    red[wave][j][0] = s[j];                                   \
                    red[wave][j][1] = q[j];                                   \
                }                                                             \
            }                                                                 \
        }                                                                     \
        __syncthreads();                                                      \
        if (tid < 2) {                                                        \
            float ts = 0.0f, tq = 0.0f;                                       \
            _Pragma("unroll") for (int w = 0; w < 4; ++w) {                   \
                ts += red[w][tid][0];                                         \
                tq += red[w][tid][1];                                         \
            }                                                                 \
            float mu = ts * (1.0f / 256.0f);                                  \
            float vr = tq * (1.0f / 256.0f) - mu * mu;                        \
            stat[tid][0] = mu;                                                \
            stat[tid][1] = rsqrtf(vr + 1e-5f);                                \
        }                                                                     \
        __syncthreads();                                                      \
    } while (0)

    LN_STATS();
    if (tid < HD) {
        const int c = tid;
        float g = ln_in_g[c], be = ln_in_b[c];
        float2 hv = hsv[c];
        hv.x = gelu_f((hv.x - stat[0][0]) * stat[0][1] * g + be);
        hv.y = gelu_f((hv.y - stat[1][0]) * stat[1][1] * g + be);
        hsv[c] = hv;
    }
    __syncthreads();

    // ---- 3 residual blocks ----
    for (int i = 0; i < 3; ++i) {
        LN_STATS();
        if (tid < HD) {
            const int c = tid;
            float gg = rb_ln_g[i * HD + c], bb = rb_ln_b[i * HD + c];
            float2 hv = hsv[c], zv;
            zv.x = (hv.x - stat[0][0]) * stat[0][1] * gg + bb;
            zv.y = (hv.y - stat[1][0]) * stat[1][1] * gg + bb;
            ztv[c] = zv;
        }
        __syncthreads();

        // w1 (bf16): K=256 -> N=512. kh = 8 slices x 32 rows; cg = 8 cols.
        {
            const unsigned short* w1 = bw + (size_t)i * (HD * 2 * HD);
            const int cg = tid & 63, kh = tid >> 6;
            const unsigned short* wp = w1 + (size_t)(kh * 32) * (2 * HD) + cg * 8;
            float a0[8] = {0, 0, 0, 0, 0, 0, 0, 0};
            float a1[8] = {0, 0, 0, 0, 0, 0, 0, 0};
#pragma unroll 8
            for (int k = 0; k < 32; ++k) {
                uint4 w = *(const uint4*)wp;
                wp += 2 * HD;
                float2 z = ztv[kh * 32 + k];
                BF8_FMA(w, z);
            }
            float* pp = part + (kh * 64 + cg) * 16;
#pragma unroll
            for (int u = 0; u < 8; ++u) {
                pp[u * 2] = a0[u];
                pp[u * 2 + 1] = a1[u];
            }
        }
        __syncthreads();
        {
            const int c2 = tid;
            const int cg = c2 >> 3, u = c2 & 7;
            float vx = rb_b1[i * 2 * HD + c2];
            float vy = vx;
#pragma unroll
            for (int kh = 0; kh < 8; ++kh) {
                const float* pp = part + (kh * 64 + cg) * 16 + u * 2;
                vx += pp[0];
                vy += pp[1];
            }
            float2 zv;
            zv.x = gelu_f(vx);
            zv.y = gelu_f(vy);
            z2tv[c2] = zv;
        }
        __syncthreads();

        // w2 (bf16): K=512 -> N=256. kh2 = 16 slices x 32 rows; cg2 = 8 cols.
        {
            const unsigned short* w2 = bw + 393216 + (size_t)i * (2 * HD * HD);
            const int cg2 = tid & 31, kh2 = tid >> 5;
            const unsigned short* wp = w2 + (size_t)(kh2 * 32) * HD + cg2 * 8;
            float a0[8] = {0, 0, 0, 0, 0, 0, 0, 0};
            float a1[8] = {0, 0, 0, 0, 0, 0, 0, 0};
#pragma unroll 8
            for (int k = 0; k < 32; ++k) {
                uint4 w = *(const uint4*)wp;
                wp += HD;
                float2 z = z2tv[kh2 * 32 + k];
                BF8_FMA(w, z);
            }
            float* pp = part + (kh2 * 32 + cg2) * 16;
#pragma unroll
            for (int u = 0; u < 8; ++u) {
                pp[u * 2] = a0[u];
                pp[u * 2 + 1] = a1[u];
            }
        }
        __syncthreads();
        if (tid < HD) {
            const int cg2 = tid >> 3, u = tid & 7;
            float vx = rb_b2[i * HD + tid];
            float vy = vx;
#pragma unroll
            for (int kh = 0; kh < 16; ++kh) {
                const float* pp = part + (kh * 32 + cg2) * 16 + u * 2;
                vx += pp[0];
                vy += pp[1];
            }
            float2 hv = hsv[tid];
            hv.x += vx;
            hv.y += vy;
            hsv[tid] = hv;
        }
        __syncthreads();
    }

    // ---- output head ----
    LN_STATS();
    if (tid < HD) {
        const int c = tid;
        float gg = out_ln_g[c], bb = out_ln_b[c];
        float2 hv = hsv[c], zv;
        zv.x = (hv.x - stat[0][0]) * stat[0][1] * gg + bb;
        zv.y = (hv.y - stat[1][0]) * stat[1][1] * gg + bb;
        ztv[c] = zv;
    }
    __syncthreads();

    // out_w1 (bf16): K=256 -> N=128. kh3 = 32 slices x 8 rows; cg3 = 8 cols.
    {
        const unsigned short* ow1 = bw + 786432;
        const int cg3 = tid & 15, kh3 = tid >> 4;
        const unsigned short* wp = ow1 + (size_t)(kh3 * 8) * (HD / 2) + cg3 * 8;
        float a0[8] = {0, 0, 0, 0, 0, 0, 0, 0};
        float a1[8] = {0, 0, 0, 0, 0, 0, 0, 0};
#pragma unroll
        for (int k = 0; k < 8; ++k) {
            uint4 w = *(const uint4*)wp;
            wp += HD / 2;
            float2 z = ztv[kh3 * 8 + k];
            BF8_FMA(w, z);
        }
        float* pp = part + (kh3 * 16 + cg3) * 16;
#pragma unroll
        for (int u = 0; u < 8; ++u) {
            pp[u * 2] = a0[u];
            pp[u * 2 + 1] = a1[u];
        }
    }
    __syncthreads();
    if (tid < HD / 2) {
        const int cg3 = tid >> 3, u = tid & 7;
        float vx = out_b1[tid];
        float vy = vx;
#pragma unroll
        for (int kh = 0; kh < 32; ++kh) {
            const float* pp = part + (kh * 16 + cg3) * 16 + u * 2;
            vx += pp[0];
            vy += pp[1];
        }
        float2 zv;
        zv.x = gelu_f(vx);
        zv.y = gelu_f(vy);
        z3tv[tid] = zv;
    }
    __syncthreads();

    // out_w2: K=128 -> N=2 (fp32, tiny)
    if (tid < HD / 2) {
        float2 z = z3tv[tid];
        float w0 = out_w2[tid * 2 + 0];
        float w1v = out_w2[tid * 2 + 1];
        float p[4];
        p[0] = z.x * w0; p[1] = z.x * w1v;
        p[2] = z.y * w0; p[3] = z.y * w1v;
#pragma unroll
        for (int off = 32; off > 0; off >>= 1) {
#pragma unroll
            for (int u = 0; u < 4; ++u) p[u] += __shfl_down(p[u], off, 64);
        }
        if (lane == 0) {
#pragma unroll
            for (int u = 0; u < 4; ++u) fin[wave][u] = p[u];
        }
    }
    __syncthreads();
    if (tid < 4) {
        int j = tid >> 1;
        int o = tid & 1;
        float s = out_b2[o] + fin[0][tid] + fin[1][tid];
        out[b * 48 + o * 8 + sub * 2 + j] = s;
    }
}

extern "C" void kernel_launch(void* const* d_in, const int* in_sizes, int n_in,
                              void* d_out, int out_size, void* d_ws, size_t ws_size,
                              hipStream_t stream) {
    const float* x        = (const float*)d_in[0];
    const float* w_in     = (const float*)d_in[1];
    const float* b_in     = (const float*)d_in[2];
    const float* ln_in_g  = (const float*)d_in[3];
    const float* ln_in_b  = (const float*)d_in[4];
    const float* rb_ln_g  = (const float*)d_in[5];
    const float* rb_ln_b  = (const float*)d_in[6];
    const float* rb_w1    = (const float*)d_in[7];
    const float* rb_b1    = (const float*)d_in[8];
    const float* rb_w2    = (const float*)d_in[9];
    const float* rb_b2    = (const float*)d_in[10];
    const float* out_ln_g = (const float*)d_in[11];
    const float* out_ln_b = (const float*)d_in[12];
    const float* out_w1   = (const float*)d_in[13];
    const float* out_b1   = (const float*)d_in[14];
    const float* out_w2   = (const float*)d_in[15];
    const float* out_b2   = (const float*)d_in[16];

    float* out = (float*)d_out;
    unsigned short* bw = (unsigned short*)d_ws;  // bf16 weights (1.6 MB)

    convert_kernel<<<400, 256, 0, stream>>>(rb_w1, rb_w2, out_w1, bw);
    hipMemsetAsync(out + 3072, 0, BN * sizeof(float), stream);
    fused_kernel<<<768, 512, 0, stream>>>(
        x, bw, w_in, b_in, ln_in_g, ln_in_b, rb_ln_g, rb_ln_b,
        rb_b1, rb_b2, out_ln_g, out_ln_b, out_b1, out_w2, out_b2, out);
}

// Round 6
// 239.233 us; speedup vs baseline: 1.0466x; 1.0466x over previous
//
#include <hip/hip_runtime.h>
#include <hip/hip_bf16.h>
#include <math.h>

#define XN 262144
#define NPAIR (XN - 1)
#define BN 64
#define HD 256
#define KK 8
#define THRC 1e-6f

__device__ __forceinline__ float gelu_f(float x) {
    return 0.5f * x * (1.0f + erff(x * 0.70710678118654752440f));
}

__device__ __forceinline__ unsigned short f2bf(float f) {
    unsigned int x = __float_as_uint(f);
    unsigned int r = (x + 0x7fffu + ((x >> 16) & 1u)) >> 16;  // RNE
    return (unsigned short)r;
}

// ---------------- Kernel 0: weights fp32 -> bf16 into workspace -------------
// bw layout (ushort): [0, 393216) rb_w1 | [393216, 786432) rb_w2 |
//                     [786432, 819200) out_w1.
__global__ __launch_bounds__(256) void convert_kernel(
    const float* __restrict__ rb_w1, const float* __restrict__ rb_w2,
    const float* __restrict__ out_w1, unsigned short* __restrict__ bw) {
    int t = blockIdx.x * 256 + threadIdx.x;
    const float* s;
    if (t < 49152) s = rb_w1 + (size_t)t * 8;
    else if (t < 98304) s = rb_w2 + (size_t)(t - 49152) * 8;
    else s = out_w1 + (size_t)(t - 98304) * 8;
    float4 a = *(const float4*)s;
    float4 b = *(const float4*)(s + 4);
    union { unsigned short u[8]; uint4 v; } r;
    r.u[0] = f2bf(a.x); r.u[1] = f2bf(a.y); r.u[2] = f2bf(a.z); r.u[3] = f2bf(a.w);
    r.u[4] = f2bf(b.x); r.u[5] = f2bf(b.y); r.u[6] = f2bf(b.z); r.u[7] = f2bf(b.w);
    *(uint4*)(bw + (size_t)t * 8) = r.v;
}

// ---------------- Kernel 1: fused count + first-8 select ---------------------
__global__ __launch_bounds__(256) void count_select_kernel(
    const float* __restrict__ x, float* __restrict__ out,
    float* __restrict__ ws_uLuR, int* __restrict__ ws_cnt) {
    __shared__ int sred[4];
    const int b = blockIdx.x >> 4;
    const int p = blockIdx.x & 15;
    const float* row = x + (size_t)b * 2 * XN;
    const int tid = threadIdx.x;
    const int lane = tid & 63, wave = tid >> 6;

    if (p == 0 && tid < 64) {
        const float* c = row + XN;
        int idxs[KK];
        float vflag[KK];
        int found = 0;
        for (int base = 0; base < NPAIR && found < KK; base += 64) {
            int i = base + lane;
            bool v = (i < NPAIR) && (fabsf(row[i] - row[i + 1]) > THRC);
            unsigned long long m = __ballot(v);
            while (m && found < KK) {
                int l = __ffsll(m) - 1;
                idxs[found] = base + l;
                vflag[found] = 1.0f;
                ++found;
                m &= (m - 1);
            }
        }
        if (found < KK) {
            for (int base = 0; base < NPAIR && found < KK; base += 64) {
                int i = base + lane;
                bool v = (i < NPAIR) && !(fabsf(row[i] - row[i + 1]) > THRC);
                unsigned long long m = __ballot(v);
                while (m && found < KK) {
                    int l = __ffsll(m) - 1;
                    idxs[found] = base + l;
                    vflag[found] = 0.0f;
                    ++found;
                    m &= (m - 1);
                }
            }
        }
        if (lane < KK) {
            int i = idxs[lane];
            float uL = row[i];
            float uR = row[i + 1];
            float fc = (c[i] + c[i + 1]) * 0.5f;
            float* o = out + b * 48;
            o[16 + lane] = uL;
            o[24 + lane] = uR;
            o[32 + lane] = fc;
            o[40 + lane] = vflag[lane];
            ws_uLuR[(b * KK + lane) * 2 + 0] = uL;
            ws_uLuR[(b * KK + lane) * 2 + 1] = uR;
        }
    }

    int cnt = 0;
    const int base0 = p * 16384;
#pragma unroll
    for (int it = 0; it < 16; ++it) {
        int e0 = base0 + ((it << 8) + tid) * 4;
        float4 f = *(const float4*)(row + e0);
        cnt += (fabsf(f.x - f.y) > THRC);
        cnt += (fabsf(f.y - f.z) > THRC);
        cnt += (fabsf(f.z - f.w) > THRC);
        if (e0 + 4 < XN) {
            float e = row[e0 + 4];
            cnt += (fabsf(f.w - e) > THRC);
        }
    }
#pragma unroll
    for (int off = 32; off > 0; off >>= 1) cnt += __shfl_down(cnt, off, 64);
    if (lane == 0) sred[wave] = cnt;
    __syncthreads();
    if (tid == 0) ws_cnt[blockIdx.x] = sred[0] + sred[1] + sred[2] + sred[3];
}

// ---------------- Kernel 2: fused speed-predictor MLP (bf16 weights) ---------
// 256 blocks x 512 threads; block = (row b, sub): 2 tokens.
// Heavy phases: ALL weight loads hoisted into a register stream (32 uint4 in
// flight per wave) so the L1/L2 port stays saturated; FMA consumes afterwards.

// FMA 8 cols x 2 tokens from one uint4 of bf16
#define BF8_FMA(w, z)                                                        \
    do {                                                                     \
        float f0, f1;                                                        \
        f0 = __uint_as_float((w).x << 16);                                   \
        f1 = __uint_as_float((w).x & 0xffff0000u);                           \
        a0[0] = fmaf(f0, (z).x, a0[0]); a1[0] = fmaf(f0, (z).y, a1[0]);      \
        a0[1] = fmaf(f1, (z).x, a0[1]); a1[1] = fmaf(f1, (z).y, a1[1]);      \
        f0 = __uint_as_float((w).y << 16);                                   \
        f1 = __uint_as_float((w).y & 0xffff0000u);                           \
        a0[2] = fmaf(f0, (z).x, a0[2]); a1[2] = fmaf(f0, (z).y, a1[2]);      \
        a0[3] = fmaf(f1, (z).x, a0[3]); a1[3] = fmaf(f1, (z).y, a1[3]);      \
        f0 = __uint_as_float((w).z << 16);                                   \
        f1 = __uint_as_float((w).z & 0xffff0000u);                           \
        a0[4] = fmaf(f0, (z).x, a0[4]); a1[4] = fmaf(f0, (z).y, a1[4]);      \
        a0[5] = fmaf(f1, (z).x, a0[5]); a1[5] = fmaf(f1, (z).y, a1[5]);      \
        f0 = __uint_as_float((w).w << 16);                                   \
        f1 = __uint_as_float((w).w & 0xffff0000u);                           \
        a0[6] = fmaf(f0, (z).x, a0[6]); a1[6] = fmaf(f0, (z).y, a1[6]);      \
        a0[7] = fmaf(f1, (z).x, a0[7]); a1[7] = fmaf(f1, (z).y, a1[7]);      \
    } while (0)

__global__ __launch_bounds__(512) void mlp_kernel(
    const float* __restrict__ ws_uLuR, const int* __restrict__ ws_cnt,
    const unsigned short* __restrict__ bw,
    const float* __restrict__ w_in, const float* __restrict__ b_in,
    const float* __restrict__ ln_in_g, const float* __restrict__ ln_in_b,
    const float* __restrict__ rb_ln_g, const float* __restrict__ rb_ln_b,
    const float* __restrict__ rb_b1, const float* __restrict__ rb_b2,
    const float* __restrict__ out_ln_g, const float* __restrict__ out_ln_b,
    const float* __restrict__ out_b1,
    const float* __restrict__ out_w2, const float* __restrict__ out_b2,
    float* __restrict__ out) {
    __shared__ float2 hsv[HD];
    __shared__ float2 ztv[HD];
    __shared__ float2 z2tv[2 * HD];
    __shared__ float2 z3tv[HD / 2];
    __shared__ float part[8192];   // 32 KB split-K partials
    __shared__ float red[8][2][2];
    __shared__ float stat[2][2];
    __shared__ float fin[2][4];

    const int tid = threadIdx.x;
    const int bid = blockIdx.x;
    const int b = bid >> 2;
    const int sub = bid & 3;
    const int wave = tid >> 6, lane = tid & 63;

    if (sub == 0 && wave == 0) {
        int v = (lane < 16) ? ws_cnt[b * 16 + lane] : 0;
#pragma unroll
        for (int off = 8; off > 0; off >>= 1) v += __shfl_down(v, off, 64);
        if (lane == 0) out[3072 + b] = (float)v;
    }

    // ---- input layer ----
    if (tid < HD) {
        const int c = tid;
        float fw[6];
#pragma unroll
        for (int f = 0; f < 6; ++f) fw[f] = w_in[f * HD + c];
        float bin = b_in[c];
        float2 hv;
        float* hvp = (float*)&hv;
#pragma unroll
        for (int j = 0; j < 2; ++j) {
            int tok = b * KK + sub * 2 + j;
            float uL = ws_uLuR[tok * 2 + 0];
            float uR = ws_uLuR[tok * 2 + 1];
            float dd = uL - uR;
            float sg = (dd > 0.0f) ? 1.0f : ((dd < 0.0f) ? -1.0f : 0.0f);
            hvp[j] = bin + uL * fw[0] + uR * fw[1] + dd * fw[2] +
                     fabsf(dd) * fw[3] + (uL + uR) * 0.5f * fw[4] + sg * fw[5];
        }
        hsv[c] = hv;
    }
    __syncthreads();

#define LN_STATS()                                                            \
    do {                                                                      \
        if (tid < HD) {                                                       \
            float2 h2 = hsv[tid];                                             \
            float s[2] = {h2.x, h2.y};                                        \
            float q[2] = {h2.x * h2.x, h2.y * h2.y};                          \
            for (int off = 32; off > 0; off >>= 1) {                          \
                _Pragma("unroll") for (int j = 0; j < 2; ++j) {               \
                    s[j] += __shfl_down(s[j], off, 64);                       \
                    q[j] += __shfl_down(q[j], off, 64);                       \
                }                                                             \
            }                                                                 \
            if (lane == 0) {                                                  \
                _Pragma("unroll") for (int j = 0; j < 2; ++j) {               \
                    red[wave][j][0] = s[j];                                   \
                    red[wave][j][1] = q[j];                                   \
                }                                                             \
            }                                                                 \
        }                                                                     \
        __syncthreads();                                                      \
        if (tid < 2) {                                                        \
            float ts = 0.0f, tq = 0.0f;                                       \
            _Pragma("unroll") for (int w = 0; w < 4; ++w) {                   \
                ts += red[w][tid][0];                                         \
                tq += red[w][tid][1];                                         \
            }                                                                 \
            float mu = ts * (1.0f / 256.0f);                                  \
            float vr = tq * (1.0f / 256.0f) - mu * mu;                        \
            stat[tid][0] = mu;                                                \
            stat[tid][1] = rsqrtf(vr + 1e-5f);                                \
        }                                                                     \
        __syncthreads();                                                      \
    } while (0)

    LN_STATS();
    if (tid < HD) {
        const int c = tid;
        float g = ln_in_g[c], be = ln_in_b[c];
        float2 hv = hsv[c];
        hv.x = gelu_f((hv.x - stat[0][0]) * stat[0][1] * g + be);
        hv.y = gelu_f((hv.y - stat[1][0]) * stat[1][1] * g + be);
        hsv[c] = hv;
    }
    __syncthreads();

    // ---- 3 residual blocks ----
    for (int i = 0; i < 3; ++i) {
        LN_STATS();
        if (tid < HD) {
            const int c = tid;
            float gg = rb_ln_g[i * HD + c], bb = rb_ln_b[i * HD + c];
            float2 hv = hsv[c], zv;
            zv.x = (hv.x - stat[0][0]) * stat[0][1] * gg + bb;
            zv.y = (hv.y - stat[1][0]) * stat[1][1] * gg + bb;
            ztv[c] = zv;
        }
        __syncthreads();

        // w1 (bf16): K=256 -> N=512. kh = 8 slices x 32 rows; cg = 8 cols.
        // All 32 loads hoisted -> single deep stream per wave.
        {
            const unsigned short* w1 = bw + (size_t)i * (HD * 2 * HD);
            const int cg = tid & 63, kh = tid >> 6;
            const unsigned short* wp = w1 + (size_t)(kh * 32) * (2 * HD) + cg * 8;
            uint4 wr[32];
#pragma unroll
            for (int k = 0; k < 32; ++k)
                wr[k] = *(const uint4*)(wp + (size_t)k * (2 * HD));
            float a0[8] = {0, 0, 0, 0, 0, 0, 0, 0};
            float a1[8] = {0, 0, 0, 0, 0, 0, 0, 0};
#pragma unroll
            for (int k = 0; k < 32; ++k) {
                uint4 w = wr[k];
                float2 z = ztv[kh * 32 + k];
                BF8_FMA(w, z);
            }
            float* pp = part + (kh * 64 + cg) * 16;
#pragma unroll
            for (int u = 0; u < 8; ++u) {
                pp[u * 2] = a0[u];
                pp[u * 2 + 1] = a1[u];
            }
        }
        __syncthreads();
        {
            const int c2 = tid;
            const int cg = c2 >> 3, u = c2 & 7;
            float vx = rb_b1[i * 2 * HD + c2];
            float vy = vx;
#pragma unroll
            for (int kh = 0; kh < 8; ++kh) {
                const float* pp = part + (kh * 64 + cg) * 16 + u * 2;
                vx += pp[0];
                vy += pp[1];
            }
            float2 zv;
            zv.x = gelu_f(vx);
            zv.y = gelu_f(vy);
            z2tv[c2] = zv;
        }
        __syncthreads();

        // w2 (bf16): K=512 -> N=256. kh2 = 16 slices x 32 rows; cg2 = 8 cols.
        {
            const unsigned short* w2 = bw + 393216 + (size_t)i * (2 * HD * HD);
            const int cg2 = tid & 31, kh2 = tid >> 5;
            const unsigned short* wp = w2 + (size_t)(kh2 * 32) * HD + cg2 * 8;
            uint4 wr[32];
#pragma unroll
            for (int k = 0; k < 32; ++k)
                wr[k] = *(const uint4*)(wp + (size_t)k * HD);
            float a0[8] = {0, 0, 0, 0, 0, 0, 0, 0};
            float a1[8] = {0, 0, 0, 0, 0, 0, 0, 0};
#pragma unroll
            for (int k = 0; k < 32; ++k) {
                uint4 w = wr[k];
                float2 z = z2tv[kh2 * 32 + k];
                BF8_FMA(w, z);
            }
            float* pp = part + (kh2 * 32 + cg2) * 16;
#pragma unroll
            for (int u = 0; u < 8; ++u) {
                pp[u * 2] = a0[u];
                pp[u * 2 + 1] = a1[u];
            }
        }
        __syncthreads();
        if (tid < HD) {
            const int cg2 = tid >> 3, u = tid & 7;
            float vx = rb_b2[i * HD + tid];
            float vy = vx;
#pragma unroll
            for (int kh = 0; kh < 16; ++kh) {
                const float* pp = part + (kh * 32 + cg2) * 16 + u * 2;
                vx += pp[0];
                vy += pp[1];
            }
            float2 hv = hsv[tid];
            hv.x += vx;
            hv.y += vy;
            hsv[tid] = hv;
        }
        __syncthreads();
    }

    // ---- output head ----
    LN_STATS();
    if (tid < HD) {
        const int c = tid;
        float gg = out_ln_g[c], bb = out_ln_b[c];
        float2 hv = hsv[c], zv;
        zv.x = (hv.x - stat[0][0]) * stat[0][1] * gg + bb;
        zv.y = (hv.y - stat[1][0]) * stat[1][1] * gg + bb;
        ztv[c] = zv;
    }
    __syncthreads();

    // out_w1 (bf16): K=256 -> N=128. kh3 = 32 slices x 8 rows; cg3 = 8 cols.
    {
        const unsigned short* ow1 = bw + 786432;
        const int cg3 = tid & 15, kh3 = tid >> 4;
        const unsigned short* wp = ow1 + (size_t)(kh3 * 8) * (HD / 2) + cg3 * 8;
        uint4 wr[8];
#pragma unroll
        for (int k = 0; k < 8; ++k)
            wr[k] = *(const uint4*)(wp + (size_t)k * (HD / 2));
        float a0[8] = {0, 0, 0, 0, 0, 0, 0, 0};
        float a1[8] = {0, 0, 0, 0, 0, 0, 0, 0};
#pragma unroll
        for (int k = 0; k < 8; ++k) {
            uint4 w = wr[k];
            float2 z = ztv[kh3 * 8 + k];
            BF8_FMA(w, z);
        }
        float* pp = part + (kh3 * 16 + cg3) * 16;
#pragma unroll
        for (int u = 0; u < 8; ++u) {
            pp[u * 2] = a0[u];
            pp[u * 2 + 1] = a1[u];
        }
    }
    __syncthreads();
    if (tid < HD / 2) {
        const int cg3 = tid >> 3, u = tid & 7;
        float vx = out_b1[tid];
        float vy = vx;
#pragma unroll
        for (int kh = 0; kh < 32; ++kh) {
            const float* pp = part + (kh * 16 + cg3) * 16 + u * 2;
            vx += pp[0];
            vy += pp[1];
        }
        float2 zv;
        zv.x = gelu_f(vx);
        zv.y = gelu_f(vy);
        z3tv[tid] = zv;
    }
    __syncthreads();

    // out_w2: K=128 -> N=2 (fp32, tiny)
    if (tid < HD / 2) {
        float2 z = z3tv[tid];
        float w0 = out_w2[tid * 2 + 0];
        float w1v = out_w2[tid * 2 + 1];
        float p[4];
        p[0] = z.x * w0; p[1] = z.x * w1v;
        p[2] = z.y * w0; p[3] = z.y * w1v;
#pragma unroll
        for (int off = 32; off > 0; off >>= 1) {
#pragma unroll
            for (int u = 0; u < 4; ++u) p[u] += __shfl_down(p[u], off, 64);
        }
        if (lane == 0) {
#pragma unroll
            for (int u = 0; u < 4; ++u) fin[wave][u] = p[u];
        }
    }
    __syncthreads();
    if (tid < 4) {
        int j = tid >> 1;
        int o = tid & 1;
        float s = out_b2[o] + fin[0][tid] + fin[1][tid];
        out[b * 48 + o * 8 + sub * 2 + j] = s;
    }
}

extern "C" void kernel_launch(void* const* d_in, const int* in_sizes, int n_in,
                              void* d_out, int out_size, void* d_ws, size_t ws_size,
                              hipStream_t stream) {
    const float* x        = (const float*)d_in[0];
    const float* w_in     = (const float*)d_in[1];
    const float* b_in     = (const float*)d_in[2];
    const float* ln_in_g  = (const float*)d_in[3];
    const float* ln_in_b  = (const float*)d_in[4];
    const float* rb_ln_g  = (const float*)d_in[5];
    const float* rb_ln_b  = (const float*)d_in[6];
    const float* rb_w1    = (const float*)d_in[7];
    const float* rb_b1    = (const float*)d_in[8];
    const float* rb_w2    = (const float*)d_in[9];
    const float* rb_b2    = (const float*)d_in[10];
    const float* out_ln_g = (const float*)d_in[11];
    const float* out_ln_b = (const float*)d_in[12];
    const float* out_w1   = (const float*)d_in[13];
    const float* out_b1   = (const float*)d_in[14];
    const float* out_w2   = (const float*)d_in[15];
    const float* out_b2   = (const float*)d_in[16];

    float* out = (float*)d_out;
    float* wsf = (float*)d_ws;                        // uLuR pairs [0..1024)
    int* wsc = (int*)(wsf + 1024);                    // 1024 partial counts
    unsigned short* bw = (unsigned short*)(wsf + 2048);  // bf16 weights (1.6 MB)

    convert_kernel<<<400, 256, 0, stream>>>(rb_w1, rb_w2, out_w1, bw);
    count_select_kernel<<<BN * 16, 256, 0, stream>>>(x, out, wsf, wsc);
    mlp_kernel<<<BN * 4, 512, 0, stream>>>(
        wsf, wsc, bw, w_in, b_in, ln_in_g, ln_in_b, rb_ln_g, rb_ln_b,
        rb_b1, rb_b2, out_ln_g, out_ln_b, out_b1, out_w2, out_b2, out);
}